// Round 1
// baseline (1065.442 us; speedup 1.0000x reference)
//
#include <hip/hip_runtime.h>
#include <hip/hip_bf16.h>
#include <math.h>

typedef unsigned short u16;
typedef __bf16 bf16x8 __attribute__((ext_vector_type(8)));
typedef float floatx4 __attribute__((ext_vector_type(4)));

#define LORA_SCALING 2.0f   // alpha 32 / rank 16

// ---------- helpers ----------
__device__ __forceinline__ u16 f2bf(float f) {
  unsigned u = __float_as_uint(f);
  u += 0x7fffu + ((u >> 16) & 1u);   // round-to-nearest-even
  return (u16)(u >> 16);
}
__device__ __forceinline__ float bflo(unsigned u) { return __uint_as_float(u << 16); }
__device__ __forceinline__ float bfhi(unsigned u) { return __uint_as_float(u & 0xffff0000u); }

// ---------- ws scale-slot zeroing (ws is poisoned 0xAA before every launch) ----------
__global__ void zero_ws_kernel(unsigned* p) {
  if (threadIdx.x < 16) p[threadIdx.x] = 0u;
}

// ---------- per-tensor absmax ----------
__global__ void absmax_kernel(const float* __restrict__ w, long long n4, unsigned* __restrict__ out) {
  long long i = (long long)blockIdx.x * blockDim.x + threadIdx.x;
  long long stride = (long long)gridDim.x * blockDim.x;
  float m = 0.f;
  for (; i < n4; i += stride) {
    float4 v = ((const float4*)w)[i];
    m = fmaxf(m, fmaxf(fmaxf(fabsf(v.x), fabsf(v.y)), fmaxf(fabsf(v.z), fabsf(v.w))));
  }
#pragma unroll
  for (int o = 32; o > 0; o >>= 1) m = fmaxf(m, __shfl_xor(m, o, 64));
  __shared__ float sm[8];
  int lane = threadIdx.x & 63, wv = threadIdx.x >> 6;
  if (lane == 0) sm[wv] = m;
  __syncthreads();
  if (threadIdx.x == 0) {
    float mm = sm[0];
    int nw = blockDim.x >> 6;
    for (int j = 1; j < nw; ++j) mm = fmaxf(mm, sm[j]);
    atomicMax(out, __float_as_uint(mm));   // nonneg floats: uint order == float order
  }
}

// ---------- fake-quant W -> bf16 ----------
__global__ void quant_kernel(const float* __restrict__ w, const unsigned* __restrict__ amax,
                             u16* __restrict__ wq, long long n4) {
  float scale = __uint_as_float(*amax) * (1.0f / 127.0f);
  long long i = (long long)blockIdx.x * blockDim.x + threadIdx.x;
  long long stride = (long long)gridDim.x * blockDim.x;
  for (; i < n4; i += stride) {
    float4 v = ((const float4*)w)[i];
    ushort4 o;
    o.x = f2bf(fminf(fmaxf(rintf(v.x / scale), -128.f), 127.f) * scale);
    o.y = f2bf(fminf(fmaxf(rintf(v.y / scale), -128.f), 127.f) * scale);
    o.z = f2bf(fminf(fmaxf(rintf(v.z / scale), -128.f), 127.f) * scale);
    o.w = f2bf(fminf(fmaxf(rintf(v.w / scale), -128.f), 127.f) * scale);
    ((ushort4*)wq)[i] = o;
  }
}

// ---------- fp32 -> bf16 convert ----------
__global__ void f2bf_kernel(const float* __restrict__ x, u16* __restrict__ xb, long long n4) {
  long long i = (long long)blockIdx.x * blockDim.x + threadIdx.x;
  long long stride = (long long)gridDim.x * blockDim.x;
  for (; i < n4; i += stride) {
    float4 v = ((const float4*)x)[i];
    ushort4 o;
    o.x = f2bf(v.x); o.y = f2bf(v.y); o.z = f2bf(v.z); o.w = f2bf(v.w);
    ((ushort4*)xb)[i] = o;
  }
}

// ---------- LoRA t = X(bf16) @ A^T(fp32), rank 16 ----------
// block 256: tid&15 = rank index r, tid>>4 = row-in-block (16 rows/block)
__global__ void lora_t_kernel(const u16* __restrict__ X, const float* __restrict__ A,
                              float* __restrict__ T, int K) {
  int r = threadIdx.x & 15;
  int mi = threadIdx.x >> 4;
  long long row = (long long)blockIdx.x * 16 + mi;
  const u16* xp = X + row * K;
  const float* ap = A + (long long)r * K;
  float acc = 0.f;
  for (int k = 0; k < K; k += 8) {
    uint4 xu = *(const uint4*)(xp + k);
    float4 a0 = *(const float4*)(ap + k);
    float4 a1 = *(const float4*)(ap + k + 4);
    acc += bflo(xu.x) * a0.x + bfhi(xu.x) * a0.y + bflo(xu.y) * a0.z + bfhi(xu.y) * a0.w;
    acc += bflo(xu.z) * a1.x + bfhi(xu.z) * a1.y + bflo(xu.w) * a1.z + bfhi(xu.w) * a1.w;
  }
  T[row * 16 + r] = acc;
}

// ---------- main GEMM: C[m][n] = A[m,:]·B[n,:] + bias[n] + 2*(T[m,:]·Bl[n,:]) (+gelu) ----------
// 128x128 tile, BK=64, 256 threads = 4 waves (2x2), each wave 4x4 frags of 16x16x32 bf16 MFMA.
// LDS layout: row-major [128][64] bf16, 16B chunks XOR-swizzled: chunk(row,c8) stores global c8^(row&7).
template<int DO_GELU>
__global__ __launch_bounds__(256)
void gemm_qlora_kernel(const u16* __restrict__ Ag, const u16* __restrict__ Bg,
                       const float* __restrict__ bias, const float* __restrict__ T,
                       const float* __restrict__ Bl, void* __restrict__ outp,
                       int M, int N, int K) {
  __shared__ u16 sA[128 * 64];
  __shared__ u16 sB[128 * 64];
  const int tid = threadIdx.x;
  const int wave = tid >> 6, lane = tid & 63;
  const int quad = lane >> 4, m16 = lane & 15;
  const int bn = blockIdx.x, bm = blockIdx.y;
  const int wm = (wave >> 1) * 64, wn = (wave & 1) * 64;
  const u16* Abase = Ag + (size_t)bm * 128 * K;
  const u16* Bbase = Bg + (size_t)bn * 128 * K;

  floatx4 acc[4][4] = {};

  for (int k0 = 0; k0 < K; k0 += 64) {
    __syncthreads();   // previous iteration's readers done
#pragma unroll
    for (int p = 0; p < 4; ++p) {
      int c = p * 256 + tid;          // 16B-chunk index in tile (1024 chunks)
      int row = c >> 3, col8 = c & 7;
      int col8s = col8 ^ (row & 7);   // fetch swizzled source so LDS holds swizzle layout
      const u16* ga = Abase + (size_t)row * K + k0 + col8s * 8;
      u16* la = sA + (size_t)(p * 256 + wave * 64) * 8;   // wave-uniform base; HW adds lane*16
      __builtin_amdgcn_global_load_lds((const __attribute__((address_space(1))) void*)ga,
                                       (__attribute__((address_space(3))) void*)la, 16, 0, 0);
      const u16* gb = Bbase + (size_t)row * K + k0 + col8s * 8;
      u16* lb = sB + (size_t)(p * 256 + wave * 64) * 8;
      __builtin_amdgcn_global_load_lds((const __attribute__((address_space(1))) void*)gb,
                                       (__attribute__((address_space(3))) void*)lb, 16, 0, 0);
    }
    __builtin_amdgcn_s_waitcnt(0x0f70);   // vmcnt(0) only
    __syncthreads();

#pragma unroll
    for (int kk = 0; kk < 2; ++kk) {
      int c8b = kk * 4 + quad;   // k chunk for this lane's quad
      bf16x8 av[4], bv[4];
#pragma unroll
      for (int mt = 0; mt < 4; ++mt) {
        int row = wm + mt * 16 + m16;
        int c8s = c8b ^ (row & 7);
        av[mt] = *(const bf16x8*)(sA + row * 64 + c8s * 8);
      }
#pragma unroll
      for (int nt = 0; nt < 4; ++nt) {
        int row = wn + nt * 16 + m16;
        int c8s = c8b ^ (row & 7);
        bv[nt] = *(const bf16x8*)(sB + row * 64 + c8s * 8);
      }
#pragma unroll
      for (int mt = 0; mt < 4; ++mt)
#pragma unroll
        for (int nt = 0; nt < 4; ++nt)
          acc[mt][nt] = __builtin_amdgcn_mfma_f32_16x16x32_bf16(av[mt], bv[nt], acc[mt][nt], 0, 0, 0);
    }
  }

  // epilogue: C/D layout row=(lane>>4)*4+reg, col=lane&15
  const float* Trow = T + (size_t)bm * 128 * 16;
  const float* Blrow = Bl + (size_t)bn * 128 * 16;
#pragma unroll
  for (int mt = 0; mt < 4; ++mt) {
#pragma unroll
    for (int r = 0; r < 4; ++r) {
      int ml = wm + mt * 16 + quad * 4 + r;
      size_t gm = (size_t)bm * 128 + ml;
      const float4* tv = (const float4*)(Trow + (size_t)ml * 16);
      float4 ta = tv[0], tb = tv[1], tc = tv[2], td = tv[3];
#pragma unroll
      for (int nt = 0; nt < 4; ++nt) {
        int nl = wn + nt * 16 + m16;
        size_t gn = (size_t)bn * 128 + nl;
        const float4* bv4 = (const float4*)(Blrow + (size_t)nl * 16);
        float4 ba = bv4[0], bb = bv4[1], bc = bv4[2], bd = bv4[3];
        float lora = ta.x * ba.x + ta.y * ba.y + ta.z * ba.z + ta.w * ba.w
                   + tb.x * bb.x + tb.y * bb.y + tb.z * bb.z + tb.w * bb.w
                   + tc.x * bc.x + tc.y * bc.y + tc.z * bc.z + tc.w * bc.w
                   + td.x * bd.x + td.y * bd.y + td.z * bd.z + td.w * bd.w;
        float v = acc[mt][nt][r] + bias[gn] + LORA_SCALING * lora;
        if (DO_GELU) {
          float g = 0.5f * v * (1.0f + erff(v * 0.70710678118654752f));
          ((u16*)outp)[gm * (size_t)N + gn] = f2bf(g);
        } else {
          ((float*)outp)[gm * (size_t)N + gn] = v;
        }
      }
    }
  }
}

// ---------- launch ----------
extern "C" void kernel_launch(void* const* d_in, const int* in_sizes, int n_in,
                              void* d_out, int out_size, void* d_ws, size_t ws_size,
                              hipStream_t stream) {
  const float* x    = (const float*)d_in[0];
  const float* W_fc = (const float*)d_in[1];
  const float* b_fc = (const float*)d_in[2];
  const float* A_fc = (const float*)d_in[3];
  const float* B_fc = (const float*)d_in[4];
  const float* W_pr = (const float*)d_in[5];
  const float* b_pr = (const float*)d_in[6];
  const float* A_pr = (const float*)d_in[7];
  const float* B_pr = (const float*)d_in[8];
  float* out = (float*)d_out;

  const int F = in_sizes[2];                 // 4096
  const int D = in_sizes[6];                 // 1024
  const int M = in_sizes[0] / D;             // 8192

  char* ws = (char*)d_ws;
  unsigned* amax = (unsigned*)ws;            // [0]=fc, [1]=proj
  u16* wq_fc = (u16*)(ws + 1024);
  u16* wq_pr = wq_fc + (size_t)F * D;
  u16* xbf   = wq_pr + (size_t)D * F;
  u16* gbf   = xbf + (size_t)M * D;
  float* t1  = (float*)(gbf + (size_t)M * F);
  float* t2  = t1 + (size_t)M * 16;

  long long wfd4 = (long long)F * D / 4;

  zero_ws_kernel<<<1, 64, 0, stream>>>(amax);
  absmax_kernel<<<256, 256, 0, stream>>>(W_fc, wfd4, amax + 0);
  absmax_kernel<<<256, 256, 0, stream>>>(W_pr, wfd4, amax + 1);
  quant_kernel<<<1024, 256, 0, stream>>>(W_fc, amax + 0, wq_fc, wfd4);
  quant_kernel<<<1024, 256, 0, stream>>>(W_pr, amax + 1, wq_pr, wfd4);
  f2bf_kernel<<<1024, 256, 0, stream>>>(x, xbf, (long long)M * D / 4);

  lora_t_kernel<<<M / 16, 256, 0, stream>>>(xbf, A_fc, t1, D);
  gemm_qlora_kernel<1><<<dim3(F / 128, M / 128), 256, 0, stream>>>(
      xbf, wq_fc, b_fc, t1, B_fc, (void*)gbf, M, F, D);
  lora_t_kernel<<<M / 16, 256, 0, stream>>>(gbf, A_pr, t2, F);
  gemm_qlora_kernel<0><<<dim3(D / 128, M / 128), 256, 0, stream>>>(
      gbf, wq_pr, b_pr, t2, B_pr, (void*)out, M, D, F);
}

// Round 2
// 961.236 us; speedup vs baseline: 1.1084x; 1.1084x over previous
//
#include <hip/hip_runtime.h>
#include <hip/hip_bf16.h>
#include <math.h>

typedef unsigned short u16;
typedef __bf16 bf16x8 __attribute__((ext_vector_type(8)));
typedef float floatx4 __attribute__((ext_vector_type(4)));

#define LORA_SCALING 2.0f   // alpha 32 / rank 16

// ---------- helpers ----------
__device__ __forceinline__ u16 f2bf(float f) {
  unsigned u = __float_as_uint(f);
  u += 0x7fffu + ((u >> 16) & 1u);   // round-to-nearest-even
  return (u16)(u >> 16);
}
__device__ __forceinline__ float bflo(unsigned u) { return __uint_as_float(u << 16); }
__device__ __forceinline__ float bfhi(unsigned u) { return __uint_as_float(u & 0xffff0000u); }

// ---------- ws scale-slot zeroing (ws is poisoned 0xAA before every launch) ----------
__global__ void zero_ws_kernel(unsigned* p) {
  if (threadIdx.x < 16) p[threadIdx.x] = 0u;
}

// ---------- per-tensor absmax ----------
__global__ void absmax_kernel(const float* __restrict__ w, long long n4, unsigned* __restrict__ out) {
  long long i = (long long)blockIdx.x * blockDim.x + threadIdx.x;
  long long stride = (long long)gridDim.x * blockDim.x;
  float m = 0.f;
  for (; i < n4; i += stride) {
    float4 v = ((const float4*)w)[i];
    m = fmaxf(m, fmaxf(fmaxf(fabsf(v.x), fabsf(v.y)), fmaxf(fabsf(v.z), fabsf(v.w))));
  }
#pragma unroll
  for (int o = 32; o > 0; o >>= 1) m = fmaxf(m, __shfl_xor(m, o, 64));
  __shared__ float sm[8];
  int lane = threadIdx.x & 63, wv = threadIdx.x >> 6;
  if (lane == 0) sm[wv] = m;
  __syncthreads();
  if (threadIdx.x == 0) {
    float mm = sm[0];
    int nw = blockDim.x >> 6;
    for (int j = 1; j < nw; ++j) mm = fmaxf(mm, sm[j]);
    atomicMax(out, __float_as_uint(mm));   // nonneg floats: uint order == float order
  }
}

// ---------- fake-quant W -> bf16 ----------
__global__ void quant_kernel(const float* __restrict__ w, const unsigned* __restrict__ amax,
                             u16* __restrict__ wq, long long n4) {
  float scale = __uint_as_float(*amax) * (1.0f / 127.0f);
  long long i = (long long)blockIdx.x * blockDim.x + threadIdx.x;
  long long stride = (long long)gridDim.x * blockDim.x;
  for (; i < n4; i += stride) {
    float4 v = ((const float4*)w)[i];
    ushort4 o;
    o.x = f2bf(fminf(fmaxf(rintf(v.x / scale), -128.f), 127.f) * scale);
    o.y = f2bf(fminf(fmaxf(rintf(v.y / scale), -128.f), 127.f) * scale);
    o.z = f2bf(fminf(fmaxf(rintf(v.z / scale), -128.f), 127.f) * scale);
    o.w = f2bf(fminf(fmaxf(rintf(v.w / scale), -128.f), 127.f) * scale);
    ((ushort4*)wq)[i] = o;
  }
}

// ---------- fp32 -> bf16 convert ----------
__global__ void f2bf_kernel(const float* __restrict__ x, u16* __restrict__ xb, long long n4) {
  long long i = (long long)blockIdx.x * blockDim.x + threadIdx.x;
  long long stride = (long long)gridDim.x * blockDim.x;
  for (; i < n4; i += stride) {
    float4 v = ((const float4*)x)[i];
    ushort4 o;
    o.x = f2bf(v.x); o.y = f2bf(v.y); o.z = f2bf(v.z); o.w = f2bf(v.w);
    ((ushort4*)xb)[i] = o;
  }
}

// ---------- LoRA t = X(bf16) @ A^T(fp32), rank 16 ----------
__global__ void lora_t_kernel(const u16* __restrict__ X, const float* __restrict__ A,
                              float* __restrict__ T, int K) {
  int r = threadIdx.x & 15;
  int mi = threadIdx.x >> 4;
  long long row = (long long)blockIdx.x * 16 + mi;
  const u16* xp = X + row * K;
  const float* ap = A + (long long)r * K;
  float acc = 0.f;
  for (int k = 0; k < K; k += 8) {
    uint4 xu = *(const uint4*)(xp + k);
    float4 a0 = *(const float4*)(ap + k);
    float4 a1 = *(const float4*)(ap + k + 4);
    acc += bflo(xu.x) * a0.x + bfhi(xu.x) * a0.y + bflo(xu.y) * a0.z + bfhi(xu.y) * a0.w;
    acc += bflo(xu.z) * a1.x + bfhi(xu.z) * a1.y + bflo(xu.w) * a1.z + bfhi(xu.w) * a1.w;
  }
  T[row * 16 + r] = acc;
}

// ---------- staging: one 128x64 bf16 tile pair (A+B) via global_load_lds ----------
__device__ __forceinline__ void stage_tiles(const u16* __restrict__ Abase,
                                            const u16* __restrict__ Bbase,
                                            int K, int k0, u16* sAB, int tid, int wave) {
#pragma unroll
  for (int p = 0; p < 4; ++p) {
    int c = p * 256 + tid;          // 16B-chunk index in tile (1024 chunks)
    int row = c >> 3;
    int col8s = (c & 7) ^ (row & 7);  // XOR swizzle
    size_t goff = (size_t)row * K + k0 + col8s * 8;
    u16* la = sAB + (size_t)(p * 256 + wave * 64) * 8;   // wave-uniform base; HW adds lane*16
    __builtin_amdgcn_global_load_lds((const __attribute__((address_space(1))) void*)(Abase + goff),
                                     (__attribute__((address_space(3))) void*)la, 16, 0, 0);
    u16* lb = la + 8192;
    __builtin_amdgcn_global_load_lds((const __attribute__((address_space(1))) void*)(Bbase + goff),
                                     (__attribute__((address_space(3))) void*)lb, 16, 0, 0);
  }
}

// ---------- main GEMM: C = A·B^T + bias + 2*(T·Bl^T) (+gelu), software-pipelined ----------
// 128x128 tile, BK=64, 256 threads = 4 waves (2x2), each wave 4x4 frags of 16x16x32 bf16 MFMA.
// Double-buffered LDS; raw s_barrier via asm so prefetch loads stay in flight across barriers.
template<int DO_GELU>
__global__ __launch_bounds__(256)
void gemm_qlora_kernel(const u16* __restrict__ Ag, const u16* __restrict__ Bg,
                       const float* __restrict__ bias, const float* __restrict__ T,
                       const float* __restrict__ Bl, void* __restrict__ outp,
                       int M, int N, int K) {
  __shared__ u16 sm[4 * 8192];   // [buf][A/B][128*64]
  const int tid = threadIdx.x;
  const int wave = tid >> 6, lane = tid & 63;
  const int quad = lane >> 4, m16 = lane & 15;

  // square-tile swizzle: 64 consecutive ids cover an 8x8 (bm,bn) square
  const int num_n = N >> 7;
  const int nsq = num_n >> 3;          // squares along n (>=1 for N>=1024)
  int id = blockIdx.x;
  int sq = id >> 6, within = id & 63;
  int sqn = sq % nsq, sqm = sq / nsq;
  int bm = sqm * 8 + (within >> 3);
  int bn = sqn * 8 + (within & 7);

  const int wm = (wave >> 1) * 64, wn = (wave & 1) * 64;
  const u16* Abase = Ag + (size_t)bm * 128 * K;
  const u16* Bbase = Bg + (size_t)bn * 128 * K;

  floatx4 acc[4][4] = {};
  const int niter = K >> 6;

  stage_tiles(Abase, Bbase, K, 0, sm, tid, wave);   // prologue: tile 0 -> buf 0

  for (int it = 0; it < niter; ++it) {
    const int buf = it & 1;
    const u16* sA = sm + buf * 16384;
    const u16* sB = sA + 8192;

    // wait for this buf's DMA (the only loads in flight), then raw barrier.
    // Prefetch issued AFTER this stays in flight through compute and the next barrier.
    asm volatile("s_waitcnt vmcnt(0)\n\ts_barrier" ::: "memory");

    if (it + 1 < niter)
      stage_tiles(Abase, Bbase, K, (it + 1) << 6, sm + (buf ^ 1) * 16384, tid, wave);

#pragma unroll
    for (int kk = 0; kk < 2; ++kk) {
      int c8b = kk * 4 + quad;
      bf16x8 av[4], bv[4];
#pragma unroll
      for (int mt = 0; mt < 4; ++mt) {
        int row = wm + mt * 16 + m16;
        av[mt] = *(const bf16x8*)(sA + row * 64 + (c8b ^ (row & 7)) * 8);
      }
#pragma unroll
      for (int nt = 0; nt < 4; ++nt) {
        int row = wn + nt * 16 + m16;
        bv[nt] = *(const bf16x8*)(sB + row * 64 + (c8b ^ (row & 7)) * 8);
      }
#pragma unroll
      for (int mt = 0; mt < 4; ++mt)
#pragma unroll
        for (int nt = 0; nt < 4; ++nt)
          acc[mt][nt] = __builtin_amdgcn_mfma_f32_16x16x32_bf16(av[mt], bv[nt], acc[mt][nt], 0, 0, 0);
    }

    // all LDS reads of this buf returned + all waves done -> safe for next DMA into it
    asm volatile("s_waitcnt lgkmcnt(0)\n\ts_barrier" ::: "memory");
  }

  // epilogue: C/D layout row=(lane>>4)*4+reg, col=lane&15
  const float* Trow = T + (size_t)bm * 128 * 16;
  const float* Blrow = Bl + (size_t)bn * 128 * 16;
#pragma unroll
  for (int mt = 0; mt < 4; ++mt) {
#pragma unroll
    for (int r = 0; r < 4; ++r) {
      int ml = wm + mt * 16 + quad * 4 + r;
      size_t gm = (size_t)bm * 128 + ml;
      const float4* tv = (const float4*)(Trow + (size_t)ml * 16);
      float4 ta = tv[0], tb = tv[1], tc = tv[2], td = tv[3];
#pragma unroll
      for (int nt = 0; nt < 4; ++nt) {
        int nl = wn + nt * 16 + m16;
        size_t gn = (size_t)bn * 128 + nl;
        const float4* bv4 = (const float4*)(Blrow + (size_t)nl * 16);
        float4 ba = bv4[0], bb = bv4[1], bc = bv4[2], bd = bv4[3];
        float lora = ta.x * ba.x + ta.y * ba.y + ta.z * ba.z + ta.w * ba.w
                   + tb.x * bb.x + tb.y * bb.y + tb.z * bb.z + tb.w * bb.w
                   + tc.x * bc.x + tc.y * bc.y + tc.z * bc.z + tc.w * bc.w
                   + td.x * bd.x + td.y * bd.y + td.z * bd.z + td.w * bd.w;
        float v = acc[mt][nt][r] + bias[gn] + LORA_SCALING * lora;
        if (DO_GELU) {
          float g = 0.5f * v * (1.0f + erff(v * 0.70710678118654752f));
          ((u16*)outp)[gm * (size_t)N + gn] = f2bf(g);
        } else {
          ((float*)outp)[gm * (size_t)N + gn] = v;
        }
      }
    }
  }
}

// ---------- launch ----------
extern "C" void kernel_launch(void* const* d_in, const int* in_sizes, int n_in,
                              void* d_out, int out_size, void* d_ws, size_t ws_size,
                              hipStream_t stream) {
  const float* x    = (const float*)d_in[0];
  const float* W_fc = (const float*)d_in[1];
  const float* b_fc = (const float*)d_in[2];
  const float* A_fc = (const float*)d_in[3];
  const float* B_fc = (const float*)d_in[4];
  const float* W_pr = (const float*)d_in[5];
  const float* b_pr = (const float*)d_in[6];
  const float* A_pr = (const float*)d_in[7];
  const float* B_pr = (const float*)d_in[8];
  float* out = (float*)d_out;

  const int F = in_sizes[2];                 // 4096
  const int D = in_sizes[6];                 // 1024
  const int M = in_sizes[0] / D;             // 8192

  char* ws = (char*)d_ws;
  unsigned* amax = (unsigned*)ws;            // [0]=fc, [1]=proj
  u16* wq_fc = (u16*)(ws + 1024);
  u16* wq_pr = wq_fc + (size_t)F * D;
  u16* xbf   = wq_pr + (size_t)D * F;
  u16* gbf   = xbf + (size_t)M * D;
  float* t1  = (float*)(gbf + (size_t)M * F);
  float* t2  = t1 + (size_t)M * 16;

  long long wfd4 = (long long)F * D / 4;

  zero_ws_kernel<<<1, 64, 0, stream>>>(amax);
  absmax_kernel<<<1024, 256, 0, stream>>>(W_fc, wfd4, amax + 0);
  absmax_kernel<<<1024, 256, 0, stream>>>(W_pr, wfd4, amax + 1);
  quant_kernel<<<2048, 256, 0, stream>>>(W_fc, amax + 0, wq_fc, wfd4);
  quant_kernel<<<2048, 256, 0, stream>>>(W_pr, amax + 1, wq_pr, wfd4);
  f2bf_kernel<<<2048, 256, 0, stream>>>(x, xbf, (long long)M * D / 4);

  lora_t_kernel<<<M / 16, 256, 0, stream>>>(xbf, A_fc, t1, D);
  gemm_qlora_kernel<1><<<dim3((M / 128) * (F / 128)), 256, 0, stream>>>(
      xbf, wq_fc, b_fc, t1, B_fc, (void*)gbf, M, F, D);
  lora_t_kernel<<<M / 16, 256, 0, stream>>>(gbf, A_pr, t2, F);
  gemm_qlora_kernel<0><<<dim3((M / 128) * (D / 128)), 256, 0, stream>>>(
      gbf, wq_pr, b_pr, t2, B_pr, (void*)out, M, D, F);
}